// Round 18
// baseline (368.226 us; speedup 1.0000x reference)
//
#include <hip/hip_runtime.h>

#define HH   128
#define H2   256
#define H3   384
#define NPT  65535      // nodes per tree (2^16 - 1)
#define TPB  512

typedef __bf16    bf16x8 __attribute__((ext_vector_type(8)));
typedef float     f32x4  __attribute__((ext_vector_type(4)));
typedef _Float16  f16x4  __attribute__((ext_vector_type(4)));
typedef _Float16  half_t;

__device__ unsigned short Wb_g[640 * 256];   // bf16 [row=output col j][k]; j<384: W_iou, else W_f

__device__ __forceinline__ float fsig(float x)  { return 1.0f / (1.0f + __expf(-x)); }
__device__ __forceinline__ float ftanh(float x) { return 1.0f - 2.0f / (__expf(2.0f * x) + 1.0f); }
__device__ __forceinline__ unsigned short f2bf(float f) {   // RNE fp32->bf16
    unsigned u = __float_as_uint(f);
    u += 0x7fffu + ((u >> 16) & 1u);
    return (unsigned short)(u >> 16);
}
__device__ __forceinline__ int swz(int off) { return off ^ (((off >> 9) & 7) << 4); }

// ---------------- weight convert ----------------
__global__ __launch_bounds__(256) void conv_k(const float* __restrict__ W_iou,
                                              const float* __restrict__ W_f)
{
    int t    = blockIdx.x * 256 + threadIdx.x;
    int base = t * 4;
    int j = base >> 8, k = base & 255;
    const float* src = (j < H3) ? (W_iou + j * H2 + k)
                                : (W_f + (j - H3) * H2 + k);
    float4 v = *(const float4*)src;
    ushort4 p;
    p.x = f2bf(v.x); p.y = f2bf(v.y); p.z = f2bf(v.z); p.w = f2bf(v.w);
    *(ushort4*)(Wb_g + base) = p;
}

#define GATES5(PI, PO, PU, PL, PR, CL, CR, HV, CV) \
    { CV = fsig(PI) * ftanh(PU) + fsig(PL) * (CL) + fsig(PR) * (CR); \
      HV = fsig(PO) * ftanh(CV); }

// ---------------- fused leaf + l=14 + l=13 ----------------
// Block b: 64 leaves -> 32 l=14 nodes -> 16 l=13 nodes, all block-local.
// l=14's A comes straight from the leaf phase (LDS); l=13's A/c are written
// into the DEAD leaf A-tile after the l=14 MFMA drains (alias, 32 KB total).
// Only l=13 writes h_bf/c_ws globally; l=14 h_bf/c_ws traffic is eliminated.
__global__ __launch_bounds__(TPB, 4) void leaf1413_k(
    const float* __restrict__ iou, const float* __restrict__ c_in,
    const float* __restrict__ b_iou, const float* __restrict__ b_f,
    float* __restrict__ h_g, half_t* __restrict__ c_ws,
    unsigned short* __restrict__ h_bf)
{
    __shared__ __align__(16) unsigned short A_lds[32 * H2];   // 16 KB leaf A; later A13+C13
    __shared__ __align__(16) half_t         C_lds[64 * HH];   // 16 KB leaf c

    const int tid = threadIdx.x;
    const int w  = tid >> 6;
    const int lr = tid & 15;
    const int lc = (tid & 63) >> 4;
    const int ee = w * 16 + lr;
    const int node0 = blockIdx.x * 32;                            // l=14 tile base
    const int tree  = node0 >> 14;
    const int lbase = tree * NPT + 32767 + 2 * (node0 & 16383);   // first leaf row
    const float bi = b_iou[ee], bo = b_iou[HH + ee], bu = b_iou[2 * HH + ee];
    const float bl = b_f[ee],   br = b_f[HH + ee];
    const unsigned short* Wp = Wb_g + ee * H2 + lc * 8;

    // ---- phase 1: leaves (elementwise), h -> h_g + LDS A-tile, c -> LDS ----
#pragma unroll
    for (int it = 0; it < 4; ++it) {
        int p   = tid + TPB * it;
        int row = p >> 5;            // 0..63
        int e4  = p & 31;
        int grow = lbase + row;
        const float* ip = iou + (size_t)grow * H3 + e4 * 4;
        float4 vi = *(const float4*)(ip);
        float4 vo = *(const float4*)(ip + HH);
        float4 vu = *(const float4*)(ip + 2 * HH);
        float4 vc = *(const float4*)(c_in + (size_t)grow * HH + e4 * 4);
        float4 bi4 = *(const float4*)(b_iou + e4 * 4);
        float4 bo4 = *(const float4*)(b_iou + HH + e4 * 4);
        float4 bu4 = *(const float4*)(b_iou + 2 * HH + e4 * 4);

        float4 hn, cn;
#define DOL(X) { float iv = fsig(vi.X + bi4.X); float ov = fsig(vo.X + bo4.X); \
                 float uv = ftanh(vu.X + bu4.X); float cv = iv * uv + vc.X;    \
                 cn.X = cv; hn.X = ov * ftanh(cv); }
        DOL(x) DOL(y) DOL(z) DOL(w)
#undef DOL
        *(float4*)(h_g + (size_t)grow * HH + e4 * 4) = hn;
        f16x4 cf; cf.x = (half_t)cn.x; cf.y = (half_t)cn.y;
        cf.z = (half_t)cn.z; cf.w = (half_t)cn.w;
        *(f16x4*)(C_lds + row * HH + e4 * 4) = cf;
        int m = row >> 1, half = row & 1;
        uint2 pk;
        pk.x = (unsigned)f2bf(hn.x) | ((unsigned)f2bf(hn.y) << 16);
        pk.y = (unsigned)f2bf(hn.z) | ((unsigned)f2bf(hn.w) << 16);
        int byte = (m * 512 + half * 256 + e4 * 8) ^ ((m & 7) << 4);
        *(uint2*)((char*)A_lds + byte) = pk;
    }
    __syncthreads();

    // ---- phase 2a: l=14 MFMA from leaf A-tile ----
    f32x4 acc[2][5] = {};
#pragma unroll
    for (int kk = 0; kk < 8; ++kk) {
        bf16x8 a0 = *(const bf16x8*)((const char*)A_lds + swz(lr * 512 + kk * 64 + lc * 16));
        bf16x8 a1 = *(const bf16x8*)((const char*)A_lds + swz((16 + lr) * 512 + kk * 64 + lc * 16));
#pragma unroll
        for (int g = 0; g < 5; ++g) {
            bf16x8 b = *(const bf16x8*)(Wp + g * HH * H2 + kk * 32);
            acc[0][g] = __builtin_amdgcn_mfma_f32_16x16x32_bf16(a0, b, acc[0][g], 0, 0, 0);
            acc[1][g] = __builtin_amdgcn_mfma_f32_16x16x32_bf16(a1, b, acc[1][g], 0, 0, 0);
        }
    }
    __syncthreads();   // all MFMA reads of leaf A-tile done -> safe to alias

    unsigned char* A13 = (unsigned char*)A_lds;                    // 8 KB: l=13 A-tile
    half_t*        C13 = (half_t*)((unsigned char*)A_lds + 8192);  // 8 KB: l=14 c

    // ---- phase 2b: l=14 epilogue -> h_g global; h/c -> aliased LDS only ----
#pragma unroll
    for (int mt = 0; mt < 2; ++mt)
#pragma unroll
        for (int r = 0; r < 4; ++r) {
            int q    = mt * 16 + lc * 4 + r;          // 0..31 within l=14 tile
            int node = node0 + q;
            int base = tree * NPT + 16383 + (node & 16383);
            float cl = (float)C_lds[(2 * q) * HH + ee];
            float cr = (float)C_lds[(2 * q + 1) * HH + ee];
            float hv, cv;
            GATES5(acc[mt][0][r] + bi, acc[mt][1][r] + bo, acc[mt][2][r] + bu,
                   acc[mt][3][r] + bl, acc[mt][4][r] + br, cl, cr, hv, cv);
            h_g[base * HH + ee] = hv;
            int j = q >> 1, half = q & 1;
            int byte = (j * 512 + half * 256 + ee * 2) ^ ((j & 7) << 4);
            *(unsigned short*)(A13 + byte) = f2bf(hv);
            C13[q * HH + ee] = (half_t)cv;
        }
    __syncthreads();

    // ---- phase 3: l=13 (16-node tile) MFMA + epilogue -> global ----
    f32x4 acc3[5] = {};
#pragma unroll
    for (int kk = 0; kk < 8; ++kk) {
        bf16x8 a0 = *(const bf16x8*)(A13 + swz(lr * 512 + kk * 64 + lc * 16));
#pragma unroll
        for (int g = 0; g < 5; ++g) {
            bf16x8 b = *(const bf16x8*)(Wp + g * HH * H2 + kk * 32);
            acc3[g] = __builtin_amdgcn_mfma_f32_16x16x32_bf16(a0, b, acc3[g], 0, 0, 0);
        }
    }
    const int n13_0 = blockIdx.x * 16;
#pragma unroll
    for (int r = 0; r < 4; ++r) {
        int j    = lc * 4 + r;                        // 0..15
        int node = n13_0 + j;
        int base = tree * NPT + 8191 + (node & 8191);
        int o    = base * HH + ee;
        float cl = (float)C13[(2 * j) * HH + ee];
        float cr = (float)C13[(2 * j + 1) * HH + ee];
        float hv, cv;
        GATES5(acc3[0][r] + bi, acc3[1][r] + bo, acc3[2][r] + bu,
               acc3[3][r] + bl, acc3[4][r] + br, cl, cr, hv, cv);
        h_g[o]  = hv;
        c_ws[o] = (half_t)cv;
        h_bf[o] = f2bf(hv);
    }
}

// ---------------- internal level (R10 exact): 32-node tile ----------------
__global__ __launch_bounds__(TPB, 4) void level_k(
    int lvl,
    const float* __restrict__ b_iou, const float* __restrict__ b_f,
    float* __restrict__ h_g, half_t* __restrict__ c_ws,
    unsigned short* __restrict__ h_bf)
{
    __shared__ __align__(16) unsigned short A_lds[32 * H2];

    const int tid = threadIdx.x;
    const int w  = tid >> 6;
    const int lr = tid & 15;
    const int lc = (tid & 63) >> 4;
    const int ee = w * 16 + lr;
    const int node0 = blockIdx.x * 32;
    const int loc0  = (1 << lvl) - 1;
    const int lmask = loc0;

#pragma unroll
    for (int it = 0; it < 2; ++it) {
        int item = tid + TPB * it;
        int m = item >> 5, u = item & 31;
        int node = node0 + m;
        int tree = node >> lvl;
        int loc  = loc0 + (node & lmask);
        int coff = (tree * NPT + 2 * loc + 1 + (u >> 4)) * HH + (u & 15) * 8;
        uint4 v = *(const uint4*)(h_bf + coff);
        *(uint4*)((char*)A_lds + swz(m * 512 + u * 16)) = v;
    }
    __syncthreads();

    int   rofs[2][4];
    float clv[2][4], crv[2][4];
#pragma unroll
    for (int mt = 0; mt < 2; ++mt)
#pragma unroll
        for (int r = 0; r < 4; ++r) {
            int node = node0 + mt * 16 + lc * 4 + r;
            int tree = node >> lvl;
            int loc  = loc0 + (node & lmask);
            int base = tree * NPT + loc;
            int lrow = base + loc + 1;
            rofs[mt][r] = base * HH + ee;
            clv[mt][r] = (float)c_ws[lrow * HH + ee];
            crv[mt][r] = (float)c_ws[lrow * HH + HH + ee];
        }

    f32x4 acc[2][5] = {};
    const unsigned short* Wp = Wb_g + ee * H2 + lc * 8;
#pragma unroll
    for (int kk = 0; kk < 8; ++kk) {
        bf16x8 a0 = *(const bf16x8*)((const char*)A_lds + swz(lr * 512 + kk * 64 + lc * 16));
        bf16x8 a1 = *(const bf16x8*)((const char*)A_lds + swz((16 + lr) * 512 + kk * 64 + lc * 16));
#pragma unroll
        for (int g = 0; g < 5; ++g) {
            bf16x8 b = *(const bf16x8*)(Wp + g * HH * H2 + kk * 32);
            acc[0][g] = __builtin_amdgcn_mfma_f32_16x16x32_bf16(a0, b, acc[0][g], 0, 0, 0);
            acc[1][g] = __builtin_amdgcn_mfma_f32_16x16x32_bf16(a1, b, acc[1][g], 0, 0, 0);
        }
    }

    const float bi = b_iou[ee], bo = b_iou[HH + ee], bu = b_iou[2 * HH + ee];
    const float bl = b_f[ee],   br = b_f[HH + ee];
#pragma unroll
    for (int mt = 0; mt < 2; ++mt)
#pragma unroll
        for (int r = 0; r < 4; ++r) {
            float hv, cv;
            GATES5(acc[mt][0][r] + bi, acc[mt][1][r] + bo, acc[mt][2][r] + bu,
                   acc[mt][3][r] + bl, acc[mt][4][r] + br, clv[mt][r], crv[mt][r], hv, cv);
            int o = rofs[mt][r];
            h_g[o]  = hv;
            c_ws[o] = (half_t)cv;
            h_bf[o] = f2bf(hv);
        }
}

// ---------------- solo tail l=5..0: one block per tree, weights in registers ----------------
__global__ __launch_bounds__(TPB, 2) void solo_k(
    const float* __restrict__ b_iou, const float* __restrict__ b_f,
    float* __restrict__ h_g, half_t* __restrict__ c_ws,
    const unsigned short* __restrict__ h_bf)
{
    __shared__ __align__(16) unsigned char hb[32768];

    const int tid = threadIdx.x;
    const int w = tid >> 6, lr = tid & 15, lc = (tid & 63) >> 4;
    const int ee = w * 16 + lr;
    const int tb = blockIdx.x * NPT;
    const float bi = b_iou[ee], bo = b_iou[HH + ee], bu = b_iou[2 * HH + ee];
    const float bl = b_f[ee],   br = b_f[HH + ee];

    bf16x8 Bf[5][8];
    const unsigned short* Wp = Wb_g + ee * H2 + lc * 8;
#pragma unroll
    for (int g = 0; g < 5; ++g)
#pragma unroll
        for (int kk = 0; kk < 8; ++kk)
            Bf[g][kk] = *(const bf16x8*)(Wp + g * HH * H2 + kk * 32);

#pragma unroll
    for (int it = 0; it < 2; ++it) {
        int p = tid + TPB * it;
        int cc = p >> 4, q = p & 15;
        uint4 v = *(const uint4*)(h_bf + (tb + 63 + cc) * HH + q * 8);
        *(uint4*)(hb + swz(p * 16)) = v;
    }

#pragma unroll 1
    for (int l = 5; l >= 0; --l) {
        const int nl     = 1 << l;
        const int loc0   = nl - 1;
        const int cloc0  = 2 * nl - 1;
        const int cbase  = (l & 1) ? 0 : 16384;
        const int obase  = cbase ^ 16384;
        const bool mt1   = (nl > 16);

        __syncthreads();

        f32x4 acc[2][5] = {};
#pragma unroll
        for (int kk = 0; kk < 8; ++kk) {
            bf16x8 a0 = *(const bf16x8*)(hb + cbase + swz(lr * 512 + kk * 64 + lc * 16));
#pragma unroll
            for (int g = 0; g < 5; ++g)
                acc[0][g] = __builtin_amdgcn_mfma_f32_16x16x32_bf16(a0, Bf[g][kk], acc[0][g], 0, 0, 0);
            if (mt1) {
                bf16x8 a1 = *(const bf16x8*)(hb + cbase + swz((16 + lr) * 512 + kk * 64 + lc * 16));
#pragma unroll
                for (int g = 0; g < 5; ++g)
                    acc[1][g] = __builtin_amdgcn_mfma_f32_16x16x32_bf16(a1, Bf[g][kk], acc[1][g], 0, 0, 0);
            }
        }
        __syncthreads();

#pragma unroll
        for (int mt = 0; mt < 2; ++mt)
#pragma unroll
            for (int r = 0; r < 4; ++r) {
                int j = mt * 16 + lc * 4 + r;
                if (j >= nl) continue;
                int row  = tb + loc0 + j;
                int lrow = tb + cloc0 + 2 * j;
                float cl = (float)c_ws[lrow * HH + ee];
                float cr = (float)c_ws[lrow * HH + HH + ee];
                float hv, cv;
                GATES5(acc[mt][0][r] + bi, acc[mt][1][r] + bo, acc[mt][2][r] + bu,
                       acc[mt][3][r] + bl, acc[mt][4][r] + br, cl, cr, hv, cv);
                h_g[row * HH + ee]  = hv;
                c_ws[row * HH + ee] = (half_t)cv;
                *(unsigned short*)(hb + obase + swz(j * 256 + ee * 2)) = f2bf(hv);
            }
    }
}

extern "C" void kernel_launch(void* const* d_in, const int* in_sizes, int n_in,
                              void* d_out, int out_size, void* d_ws, size_t ws_size,
                              hipStream_t stream)
{
    const float* iou   = (const float*)d_in[0];
    const float* c_in  = (const float*)d_in[2];
    const float* W_iou = (const float*)d_in[3];
    const float* b_iou = (const float*)d_in[4];
    const float* W_f   = (const float*)d_in[5];
    const float* b_f   = (const float*)d_in[6];
    float* h_out = (float*)d_out;
    half_t* c_ws = (half_t*)d_ws;                                                       // 67 MiB f16 c
    unsigned short* h_bf = (unsigned short*)((char*)d_ws + (size_t)72 * 1024 * 1024);   // 67 MiB bf16 h

    conv_k<<<160, 256, 0, stream>>>(W_iou, W_f);
    leaf1413_k<<<2048, TPB, 0, stream>>>(iou, c_in, b_iou, b_f, h_out, c_ws, h_bf);  // leaves + l=14 + l=13
    for (int l = 12; l >= 6; --l) {
        int blocks = (4 << l) / 32;
        level_k<<<blocks, TPB, 0, stream>>>(l, b_iou, b_f, h_out, c_ws, h_bf);
    }
    solo_k<<<4, TPB, 0, stream>>>(b_iou, b_f, h_out, c_ws, h_bf);
}